// Round 6
// baseline (135.126 us; speedup 1.0000x reference)
//
#include <hip/hip_runtime.h>
#include <hip/hip_bf16.h>

// GeneralAttention: fp32 in / fp32 out.
//   q,k,v: [2, 2048, 1024] f32; W_proj: [1024,1024] f32; b_proj: [1024] f32
// ROUND-6 DIAGNOSTIC: attn single-launch (best-known); GEMM (R3-exact
// BK=128) launched TWICE (idempotent) -> dur_us - 118.9 ~= one warm GEMM.
// Completes the attn/GEMM split started in round 5 (warm attn = 15.6 us).
#define B_SZ 2
#define T_SZ 2048
#define NE   1024
#define NH   16
#define HD   64
#define WIN  64
#define QT   64          // queries per attention tile
#define KT   192         // keys staged per tile = QT + 2*WIN
#define GM   4096        // B*T
#define GN   1024
#define GK   1024
#define KPAD 72          // Ks row stride (36 dw == 4 mod 32 -> spread banks)
#define VPAD 200         // Vt/Ps row stride (100 dw == 4 mod 32)

__device__ ushort Wb_static[GN * GK];   // 2 MiB bf16 W copy (rewritten every launch)

// ---------- bf16 <-> f32 helpers ----------
__device__ __forceinline__ uint pack2(float lo, float hi) {
    uint r;
    asm("v_cvt_pk_bf16_f32 %0, %1, %2" : "=v"(r) : "v"(lo), "v"(hi));
    return r;
}
__device__ __forceinline__ uint4 pack8(float4 a, float4 b) {
    return make_uint4(pack2(a.x, a.y), pack2(a.z, a.w),
                      pack2(b.x, b.y), pack2(b.z, b.w));
}

typedef __attribute__((ext_vector_type(8))) short frag_ab;   // 8 bf16
typedef __attribute__((ext_vector_type(4))) float frag_cd;   // 4 fp32
union FragU { frag_ab f; uint u[4]; };

// LDS-only barrier: drains ds ops (lgkmcnt) but NOT global loads (vmcnt).
#define LDS_BAR() do {                                        \
    asm volatile("s_waitcnt lgkmcnt(0)" ::: "memory");        \
    __builtin_amdgcn_s_barrier();                             \
    asm volatile("" ::: "memory");                            \
} while (0)

// =====================================================================
// Kernel 1: MFMA windowed attention + fused W fp32->bf16 convert.
// (round-4/5 T14 version: V kept in regs across QK^T, raw lgkm barriers)
// =====================================================================
__global__ __launch_bounds__(256, 3) void attn_mfma_kernel(
    const float* __restrict__ q, const float* __restrict__ k,
    const float* __restrict__ v, const float* __restrict__ W,
    ushort* __restrict__ y)
{
    __shared__ __attribute__((aligned(16))) ushort pool[KT * KPAD + HD * VPAD]; // 52 KiB
    ushort* Ks = pool;                  // [KT][KPAD]  27.0 KiB (dead after S-phase)
    ushort* Vt = pool + KT * KPAD;      // [HD][VPAD]  25.0 KiB (swizzled)
    ushort* Ps = pool;                  // [QT][VPAD]  25.0 KiB — aliases Ks

    // flat grid 0..1023; XCD-bijective swizzle (1024 = 8 XCD * 128)
    const int bid = blockIdx.x;
    const int swz = ((bid & 7) << 7) | (bid >> 3);
    const int qs  = (swz & 31) * QT;
    const int h   = (swz >> 5) & 15;
    const int b   = swz >> 9;
    const int t   = threadIdx.x;
    const int kstart = qs - WIN;

    const int wv   = t >> 6;     // wave 0..3
    const int L    = t & 63;
    const int r16  = L & 15;
    const int quad = L >> 4;

    // ---- issue Q loads first (latency overlaps staging below) ----
    float4 qf0, qf1, qg0, qg1;
    {
        const float* qrow = q + ((size_t)(b * T_SZ + qs + wv * 16 + r16)) * NE + h * HD;
        const float4* p0 = (const float4*)(qrow + quad * 8);
        const float4* p1 = (const float4*)(qrow + 32 + quad * 8);
        qf0 = p0[0]; qf1 = p0[1]; qg0 = p1[0]; qg1 = p1[1];
    }

    // ---- fused W convert: this block converts 1024 elems (4/thread) ----
    {
        const int idx = bid * 256 + t;                                   // float4 index
        const float4 f = ((const float4*)W)[idx];
        ((uint2*)Wb_static)[idx] = make_uint2(pack2(f.x, f.y), pack2(f.z, f.w));
    }

    // ---- stage K (row-major) now; V loads issued, kept in regs ----
    float4 va[6], vb[6];
#pragma unroll
    for (int i = 0; i < 6; ++i) {
        const int c  = t + 256 * i;     // KT*8 = 1536 = 6*256 exactly
        const int j  = c >> 3;          // key 0..191
        const int cc = c & 7;           // dim-chunk
        const int d8 = cc * 8;
        const int jg = kstart + j;
        const int jc = min(max(jg, 0), T_SZ - 1);
        const size_t off = ((size_t)(b * T_SZ + jc)) * NE + h * HD + d8;
        const float4* kp = (const float4*)(k + off);
        const float4* vp = (const float4*)(v + off);
        va[i] = vp[0]; vb[i] = vp[1];           // issue V loads, consume later
        const float4 k0 = kp[0], k1 = kp[1];
        *(uint4*)&Ks[j * KPAD + d8] = pack8(k0, k1);
    }

    // ---- Q A-frags (pre-scaled by log2e/8 so softmax uses raw exp2) ----
    const float QSC = 0.125f * 1.44269504f;
    frag_ab aq0, aq1;
    {
        FragU u0, u1;
        u0.u[0] = pack2(qf0.x * QSC, qf0.y * QSC);
        u0.u[1] = pack2(qf0.z * QSC, qf0.w * QSC);
        u0.u[2] = pack2(qf1.x * QSC, qf1.y * QSC);
        u0.u[3] = pack2(qf1.z * QSC, qf1.w * QSC);
        u1.u[0] = pack2(qg0.x * QSC, qg0.y * QSC);
        u1.u[1] = pack2(qg0.z * QSC, qg0.w * QSC);
        u1.u[2] = pack2(qg1.x * QSC, qg1.y * QSC);
        u1.u[3] = pack2(qg1.z * QSC, qg1.w * QSC);
        aq0 = u0.f; aq1 = u1.f;
    }
    LDS_BAR();    // Ks visible to all waves; V global loads stay in flight

    // ---- S = Q K^T ----
    frag_cd sacc[12];
#pragma unroll
    for (int nb = 0; nb < 12; ++nb) sacc[nb] = (frag_cd){0,0,0,0};
    __builtin_amdgcn_s_setprio(1);
#pragma unroll
    for (int nb = 0; nb < 12; ++nb) {
        const frag_ab b0 = *(const frag_ab*)&Ks[(nb * 16 + r16) * KPAD + quad * 8];
        const frag_ab b1 = *(const frag_ab*)&Ks[(nb * 16 + r16) * KPAD + 32 + quad * 8];
        sacc[nb] = __builtin_amdgcn_mfma_f32_16x16x32_bf16(aq0, b0, sacc[nb], 0, 0, 0);
        sacc[nb] = __builtin_amdgcn_mfma_f32_16x16x32_bf16(aq1, b1, sacc[nb], 0, 0, 0);
    }
    __builtin_amdgcn_s_setprio(0);

    // ---- masked fixed-ref softmax in registers (exp2, unsigned-range mask) ----
    const int base_m = wv * 16 + quad * 4;
    float l[4] = {0.f, 0.f, 0.f, 0.f};
#pragma unroll
    for (int nb = 0; nb < 12; ++nb) {
        const int jl = nb * 16 + r16;
        const int jg = kstart + jl;
        const bool jg_ok = (jg >= 0) & (jg < T_SZ);
#pragma unroll
        for (int r = 0; r < 4; ++r) {
            const int mrow = base_m + r;
            const bool valid = jg_ok & ((uint)(jl - mrow) <= 2u * WIN);
            const float p = valid ? exp2f(sacc[nb][r]) : 0.0f;
            l[r] += p;
            sacc[nb][r] = p;
        }
    }
#pragma unroll
    for (int r = 0; r < 4; ++r) {
        l[r] += __shfl_xor(l[r], 1);
        l[r] += __shfl_xor(l[r], 2);
        l[r] += __shfl_xor(l[r], 4);
        l[r] += __shfl_xor(l[r], 8);
    }

    // ---- NOW consume V: pack + transposed swizzled store to Vt ----
#pragma unroll
    for (int i = 0; i < 6; ++i) {
        const int c  = t + 256 * i;
        const int j  = c >> 3;
        const int cc = c & 7;
        const int d8 = cc * 8;
        ushort* vtc = &Vt[d8 * VPAD + (((j >> 3) ^ cc) * 8 + (j & 7))];
        const uint p01 = pack2(va[i].x, va[i].y);
        const uint p23 = pack2(va[i].z, va[i].w);
        const uint p45 = pack2(vb[i].x, vb[i].y);
        const uint p67 = pack2(vb[i].z, vb[i].w);
        vtc[0 * VPAD] = (ushort)p01; vtc[1 * VPAD] = (ushort)(p01 >> 16);
        vtc[2 * VPAD] = (ushort)p23; vtc[3 * VPAD] = (ushort)(p23 >> 16);
        vtc[4 * VPAD] = (ushort)p45; vtc[5 * VPAD] = (ushort)(p45 >> 16);
        vtc[6 * VPAD] = (ushort)p67; vtc[7 * VPAD] = (ushort)(p67 >> 16);
    }

    LDS_BAR();   // all waves' Ks reads done; safe to overwrite with Ps
#pragma unroll
    for (int nb = 0; nb < 12; ++nb) {
        const int jl = nb * 16 + r16;
        const uint p01 = pack2(sacc[nb][0], sacc[nb][1]);
        const uint p23 = pack2(sacc[nb][2], sacc[nb][3]);
        Ps[(base_m + 0) * VPAD + jl] = (ushort)p01;
        Ps[(base_m + 1) * VPAD + jl] = (ushort)(p01 >> 16);
        Ps[(base_m + 2) * VPAD + jl] = (ushort)p23;
        Ps[(base_m + 3) * VPAD + jl] = (ushort)(p23 >> 16);
    }
    LDS_BAR();   // Ps + Vt complete and visible

    // ---- O = P V ----
    frag_ab ap[6];
#pragma unroll
    for (int kb = 0; kb < 6; ++kb)
        ap[kb] = *(const frag_ab*)&Ps[(wv * 16 + r16) * VPAD + kb * 32 + quad * 8];

    frag_cd oacc[4];
#pragma unroll
    for (int nb = 0; nb < 4; ++nb) oacc[nb] = (frag_cd){0,0,0,0};
    __builtin_amdgcn_s_setprio(1);
#pragma unroll
    for (int nb = 0; nb < 4; ++nb) {
        const int dr  = nb * 16 + r16;
        const int dsw = (dr >> 3) & 7;
#pragma unroll
        for (int kb = 0; kb < 6; ++kb) {
            const frag_ab bv = *(const frag_ab*)&Vt[dr * VPAD + (((kb * 4 + quad) ^ dsw) * 8)];
            oacc[nb] = __builtin_amdgcn_mfma_f32_16x16x32_bf16(ap[kb], bv, oacc[nb], 0, 0, 0);
        }
    }
    __builtin_amdgcn_s_setprio(0);

    // ---- normalize + store y (bf16) ----
    float inv[4];
#pragma unroll
    for (int r = 0; r < 4; ++r) inv[r] = 1.0f / l[r];
#pragma unroll
    for (int nb = 0; nb < 4; ++nb) {
        const int d  = nb * 16 + r16;
        const uint p01 = pack2(oacc[nb][0] * inv[0], oacc[nb][1] * inv[1]);
        const uint p23 = pack2(oacc[nb][2] * inv[2], oacc[nb][3] * inv[3]);
        const size_t rb = (size_t)(b * T_SZ + qs + base_m) * NE + h * HD + d;
        y[rb + 0 * NE] = (ushort)p01;
        y[rb + 1 * NE] = (ushort)(p01 >> 16);
        y[rb + 2 * NE] = (ushort)p23;
        y[rb + 3 * NE] = (ushort)(p23 >> 16);
    }
}

// =====================================================================
// Kernel 2: LDS-staged NT GEMM, 128m x 64n tile, BK=128 (round-3 exact).
// 512 blocks flat grid with XCD swizzle. 4 waves as 2m x 2n (wave 64x32).
// LDS 48 KiB. 32 MFMA per wave between barrier pairs (m97 parity).
// XOR chunk swizzle keeps ds_read_b128 conflict-free.
// =====================================================================
__global__ __launch_bounds__(256, 2) void proj_gemm_kernel(
    const ushort* __restrict__ A,
    const float* __restrict__ bias, float* __restrict__ C)
{
    __shared__ __attribute__((aligned(16))) ushort As[128 * 128]; // 32 KiB
    __shared__ __attribute__((aligned(16))) ushort Bs[64 * 128];  // 16 KiB

    const ushort* Bw = Wb_static;
    const int t   = threadIdx.x;
    const int bid = blockIdx.x;            // 0..511 flat
    const int swz = ((bid & 7) << 6) | (bid >> 3);  // 512 = 8 XCD * 64
    const int tile_n = swz & 15;           // 0..15
    const int tile_m = swz >> 4;           // 0..31
    const int lane   = t & 63;
    const int wv     = t >> 6;
    const int wm     = wv >> 1;      // 0..1
    const int wn     = wv & 1;       // 0..1
    const int r16    = lane & 15;
    const int quad   = lane >> 4;

    frag_cd acc[4][2];
#pragma unroll
    for (int mi = 0; mi < 4; ++mi)
#pragma unroll
        for (int ni = 0; ni < 2; ++ni)
            acc[mi][ni] = (frag_cd){0.0f, 0.0f, 0.0f, 0.0f};

    const int fm = wm * 64 + r16;            // A row base (add mi*16)
    const int fn = wn * 32 + r16;            // B row base (add ni*16)
    const int sw = r16 & 7;                  // XOR key (row&7 of all frag rows)

    for (int k0 = 0; k0 < GK; k0 += 128) {
#pragma unroll
        for (int i = 0; i < 8; ++i) {
            const int c   = t + 256 * i;
            const int row = c >> 4;
            const int src = ((c & 15) ^ (row & 7)) * 8;   // XOR touches low 3 bits only
            __builtin_amdgcn_global_load_lds(
                (const __attribute__((address_space(1))) unsigned int*)
                    (A + (size_t)(tile_m * 128 + row) * GK + k0 + src),
                (__attribute__((address_space(3))) unsigned int*)(As + c * 8), 16, 0, 0);
        }
#pragma unroll
        for (int i = 0; i < 4; ++i) {
            const int c   = t + 256 * i;
            const int row = c >> 4;
            const int src = ((c & 15) ^ (row & 7)) * 8;
            __builtin_amdgcn_global_load_lds(
                (const __attribute__((address_space(1))) unsigned int*)
                    (Bw + (size_t)(tile_n * 64 + row) * GK + k0 + src),
                (__attribute__((address_space(3))) unsigned int*)(Bs + c * 8), 16, 0, 0);
        }
        __syncthreads();

#pragma unroll
        for (int ks = 0; ks < 4; ++ks) {
            const int cidx = (((ks * 4) + quad) ^ sw) * 8;  // LDS chunk for global k-slice
            frag_ab af[4], bfr[2];
#pragma unroll
            for (int mi = 0; mi < 4; ++mi)
                af[mi] = *(const frag_ab*)&As[(fm + mi * 16) * 128 + cidx];
#pragma unroll
            for (int ni = 0; ni < 2; ++ni)
                bfr[ni] = *(const frag_ab*)&Bs[(fn + ni * 16) * 128 + cidx];
#pragma unroll
            for (int mi = 0; mi < 4; ++mi)
#pragma unroll
                for (int ni = 0; ni < 2; ++ni)
                    acc[mi][ni] = __builtin_amdgcn_mfma_f32_16x16x32_bf16(
                        af[mi], bfr[ni], acc[mi][ni], 0, 0, 0);
        }

        __syncthreads();
    }

#pragma unroll
    for (int mi = 0; mi < 4; ++mi) {
#pragma unroll
        for (int ni = 0; ni < 2; ++ni) {
            const int rbase = tile_m * 128 + wm * 64 + mi * 16 + quad * 4;
            const int cg    = tile_n * 64 + wn * 32 + ni * 16 + r16;
            const float bv  = bias[cg];
#pragma unroll
            for (int r = 0; r < 4; ++r)
                C[(size_t)(rbase + r) * GN + cg] = acc[mi][ni][r] + bv;
        }
    }
}

extern "C" void kernel_launch(void* const* d_in, const int* in_sizes, int n_in,
                              void* d_out, int out_size, void* d_ws, size_t ws_size,
                              hipStream_t stream) {
    (void)in_sizes; (void)n_in; (void)out_size; (void)ws_size;
    const float* q    = (const float*)d_in[0];
    const float* k    = (const float*)d_in[1];
    const float* v    = (const float*)d_in[2];
    const float* W    = (const float*)d_in[3];
    const float* bias = (const float*)d_in[4];
    float*  out = (float*)d_out;
    ushort* y   = (ushort*)d_ws;   // 8 MiB bf16 scratch

    dim3 g1(1024);                         // flat; XCD-swizzled inside
    attn_mfma_kernel<<<g1, 256, 0, stream>>>(q, k, v, W, y);

    dim3 g2(512);                          // flat; XCD-swizzled inside
    // DIAGNOSTIC: GEMM launched twice (idempotent). dur_us delta vs the
    // single-launch round-3 build (118.9) measures one warm GEMM pass.
    proj_gemm_kernel<<<g2, 256, 0, stream>>>(y, bias, out);
    proj_gemm_kernel<<<g2, 256, 0, stream>>>(y, bias, out);
}

// Round 7
// 118.282 us; speedup vs baseline: 1.1424x; 1.1424x over previous
//
#include <hip/hip_runtime.h>
#include <hip/hip_bf16.h>

// GeneralAttention: fp32 in / fp32 out.
//   q,k,v: [2, 2048, 1024] f32; W_proj: [1024,1024] f32; b_proj: [1024] f32
// Round-7: (a) attn skips fully-masked key-blocks (9/12 QK, 5/6 PV,
// wave-uniform, bit-identical); (b) GEMM gets the CORRECT 2-phase
// counted-vmcnt pipeline (R4's version was broken by __syncthreads'
// implicit vmcnt(0) drain of the prefetch).
#define B_SZ 2
#define T_SZ 2048
#define NE   1024
#define NH   16
#define HD   64
#define WIN  64
#define QT   64          // queries per attention tile
#define KT   192         // keys staged per tile = QT + 2*WIN
#define GM   4096        // B*T
#define GN   1024
#define GK   1024
#define KPAD 72          // Ks row stride (36 dw == 4 mod 32 -> spread banks)
#define VPAD 200         // Vt/Ps row stride (100 dw == 4 mod 32)

__device__ ushort Wb_static[GN * GK];   // 2 MiB bf16 W copy (rewritten every launch)

// ---------- bf16 <-> f32 helpers ----------
__device__ __forceinline__ uint pack2(float lo, float hi) {
    uint r;
    asm("v_cvt_pk_bf16_f32 %0, %1, %2" : "=v"(r) : "v"(lo), "v"(hi));
    return r;
}
__device__ __forceinline__ uint4 pack8(float4 a, float4 b) {
    return make_uint4(pack2(a.x, a.y), pack2(a.z, a.w),
                      pack2(b.x, b.y), pack2(b.z, b.w));
}

typedef __attribute__((ext_vector_type(8))) short frag_ab;   // 8 bf16
typedef __attribute__((ext_vector_type(4))) float frag_cd;   // 4 fp32
union FragU { frag_ab f; uint u[4]; };

// LDS-only barrier: drains this wave's ds ops (lgkmcnt) then barriers.
// Does NOT drain vmcnt -> in-flight global/global_load_lds survive.
#define LDS_BAR() do {                                        \
    asm volatile("s_waitcnt lgkmcnt(0)" ::: "memory");        \
    __builtin_amdgcn_s_barrier();                             \
    asm volatile("" ::: "memory");                            \
} while (0)

// Counted vmem wait + barrier: waits until <= N vmem ops outstanding
// (i.e. the oldest ones -- the current tile's loads -- have landed),
// then barriers. Never drains the just-issued prefetch.
#define VM_BAR(N) do {                                        \
    asm volatile("s_waitcnt vmcnt(" #N ")" ::: "memory");     \
    __builtin_amdgcn_s_barrier();                             \
    asm volatile("" ::: "memory");                            \
} while (0)

// =====================================================================
// Kernel 1: MFMA windowed attention + fused W fp32->bf16 convert.
// Wave wv owns queries [16wv,16wv+15]; valid keys [16wv,16wv+143] ->
// QK/softmax over nb = wv..wv+8 (9 of 12 blocks), PV over kb =
// (wv>>1)..(wv>>1)+4 (5 of 6). One read-but-unwritten Ps block per wave
// is zero-filled. Bit-identical to the full computation.
// =====================================================================
__global__ __launch_bounds__(256, 3) void attn_mfma_kernel(
    const float* __restrict__ q, const float* __restrict__ k,
    const float* __restrict__ v, const float* __restrict__ W,
    ushort* __restrict__ y)
{
    __shared__ __attribute__((aligned(16))) ushort pool[KT * KPAD + HD * VPAD]; // 52 KiB
    ushort* Ks = pool;                  // [KT][KPAD]  27.0 KiB (dead after S-phase)
    ushort* Vt = pool + KT * KPAD;      // [HD][VPAD]  25.0 KiB (swizzled)
    ushort* Ps = pool;                  // [QT][VPAD]  25.0 KiB — aliases Ks

    // flat grid 0..1023; XCD-bijective swizzle (1024 = 8 XCD * 128)
    const int bid = blockIdx.x;
    const int swz = ((bid & 7) << 7) | (bid >> 3);
    const int qs  = (swz & 31) * QT;
    const int h   = (swz >> 5) & 15;
    const int b   = swz >> 9;
    const int t   = threadIdx.x;
    const int kstart = qs - WIN;

    const int wv   = t >> 6;     // wave 0..3
    const int L    = t & 63;
    const int r16  = L & 15;
    const int quad = L >> 4;

    // ---- issue Q loads first (latency overlaps staging below) ----
    float4 qf0, qf1, qg0, qg1;
    {
        const float* qrow = q + ((size_t)(b * T_SZ + qs + wv * 16 + r16)) * NE + h * HD;
        const float4* p0 = (const float4*)(qrow + quad * 8);
        const float4* p1 = (const float4*)(qrow + 32 + quad * 8);
        qf0 = p0[0]; qf1 = p0[1]; qg0 = p1[0]; qg1 = p1[1];
    }

    // ---- fused W convert: this block converts 1024 elems (4/thread) ----
    {
        const int idx = bid * 256 + t;                                   // float4 index
        const float4 f = ((const float4*)W)[idx];
        ((uint2*)Wb_static)[idx] = make_uint2(pack2(f.x, f.y), pack2(f.z, f.w));
    }

    // ---- stage K (row-major) now; V loads issued, kept in regs ----
    float4 va[6], vb[6];
#pragma unroll
    for (int i = 0; i < 6; ++i) {
        const int c  = t + 256 * i;     // KT*8 = 1536 = 6*256 exactly
        const int j  = c >> 3;          // key 0..191
        const int cc = c & 7;           // dim-chunk
        const int d8 = cc * 8;
        const int jg = kstart + j;
        const int jc = min(max(jg, 0), T_SZ - 1);
        const size_t off = ((size_t)(b * T_SZ + jc)) * NE + h * HD + d8;
        const float4* kp = (const float4*)(k + off);
        const float4* vp = (const float4*)(v + off);
        va[i] = vp[0]; vb[i] = vp[1];           // issue V loads, consume later
        const float4 k0 = kp[0], k1 = kp[1];
        *(uint4*)&Ks[j * KPAD + d8] = pack8(k0, k1);
    }

    // ---- Q A-frags (pre-scaled by log2e/8 so softmax uses raw exp2) ----
    const float QSC = 0.125f * 1.44269504f;
    frag_ab aq0, aq1;
    {
        FragU u0, u1;
        u0.u[0] = pack2(qf0.x * QSC, qf0.y * QSC);
        u0.u[1] = pack2(qf0.z * QSC, qf0.w * QSC);
        u0.u[2] = pack2(qf1.x * QSC, qf1.y * QSC);
        u0.u[3] = pack2(qf1.z * QSC, qf1.w * QSC);
        u1.u[0] = pack2(qg0.x * QSC, qg0.y * QSC);
        u1.u[1] = pack2(qg0.z * QSC, qg0.w * QSC);
        u1.u[2] = pack2(qg1.x * QSC, qg1.y * QSC);
        u1.u[3] = pack2(qg1.z * QSC, qg1.w * QSC);
        aq0 = u0.f; aq1 = u1.f;
    }
    LDS_BAR();    // Ks visible to all waves; V global loads stay in flight

    // ---- S = Q K^T (9 valid key-blocks: nb = wv..wv+8) ----
    frag_cd sacc[9];
#pragma unroll
    for (int i = 0; i < 9; ++i) sacc[i] = (frag_cd){0,0,0,0};
    __builtin_amdgcn_s_setprio(1);
#pragma unroll
    for (int i = 0; i < 9; ++i) {
        const int nb = wv + i;
        const frag_ab b0 = *(const frag_ab*)&Ks[(nb * 16 + r16) * KPAD + quad * 8];
        const frag_ab b1 = *(const frag_ab*)&Ks[(nb * 16 + r16) * KPAD + 32 + quad * 8];
        sacc[i] = __builtin_amdgcn_mfma_f32_16x16x32_bf16(aq0, b0, sacc[i], 0, 0, 0);
        sacc[i] = __builtin_amdgcn_mfma_f32_16x16x32_bf16(aq1, b1, sacc[i], 0, 0, 0);
    }
    __builtin_amdgcn_s_setprio(0);

    // ---- masked fixed-ref softmax in registers (exp2, unsigned-range mask) ----
    const int base_m = wv * 16 + quad * 4;
    float l[4] = {0.f, 0.f, 0.f, 0.f};
#pragma unroll
    for (int i = 0; i < 9; ++i) {
        const int jl = (wv + i) * 16 + r16;
        const int jg = kstart + jl;
        const bool jg_ok = (jg >= 0) & (jg < T_SZ);
#pragma unroll
        for (int r = 0; r < 4; ++r) {
            const int mrow = base_m + r;
            const bool valid = jg_ok & ((uint)(jl - mrow) <= 2u * WIN);
            const float p = valid ? exp2f(sacc[i][r]) : 0.0f;
            l[r] += p;
            sacc[i][r] = p;
        }
    }
#pragma unroll
    for (int r = 0; r < 4; ++r) {
        l[r] += __shfl_xor(l[r], 1);
        l[r] += __shfl_xor(l[r], 2);
        l[r] += __shfl_xor(l[r], 4);
        l[r] += __shfl_xor(l[r], 8);
    }

    // ---- NOW consume V: pack + transposed swizzled store to Vt ----
#pragma unroll
    for (int i = 0; i < 6; ++i) {
        const int c  = t + 256 * i;
        const int j  = c >> 3;
        const int cc = c & 7;
        const int d8 = cc * 8;
        ushort* vtc = &Vt[d8 * VPAD + (((j >> 3) ^ cc) * 8 + (j & 7))];
        const uint p01 = pack2(va[i].x, va[i].y);
        const uint p23 = pack2(va[i].z, va[i].w);
        const uint p45 = pack2(vb[i].x, vb[i].y);
        const uint p67 = pack2(vb[i].z, vb[i].w);
        vtc[0 * VPAD] = (ushort)p01; vtc[1 * VPAD] = (ushort)(p01 >> 16);
        vtc[2 * VPAD] = (ushort)p23; vtc[3 * VPAD] = (ushort)(p23 >> 16);
        vtc[4 * VPAD] = (ushort)p45; vtc[5 * VPAD] = (ushort)(p45 >> 16);
        vtc[6 * VPAD] = (ushort)p67; vtc[7 * VPAD] = (ushort)(p67 >> 16);
    }

    LDS_BAR();   // all waves' Ks reads done; safe to overwrite with Ps
    // valid blocks nb = wv..wv+8; PV reads nb = (wv&~1)..(wv&~1)+9,
    // so exactly one read-but-unwritten block per wave -> zero-fill it.
#pragma unroll
    for (int i = 0; i < 9; ++i) {
        const int jl = (wv + i) * 16 + r16;
        const uint p01 = pack2(sacc[i][0], sacc[i][1]);
        const uint p23 = pack2(sacc[i][2], sacc[i][3]);
        Ps[(base_m + 0) * VPAD + jl] = (ushort)p01;
        Ps[(base_m + 1) * VPAD + jl] = (ushort)(p01 >> 16);
        Ps[(base_m + 2) * VPAD + jl] = (ushort)p23;
        Ps[(base_m + 3) * VPAD + jl] = (ushort)(p23 >> 16);
    }
    {
        const int zb = (wv & 1) ? (wv - 1) : (wv + 9);   // 0->9, 1->0, 2->11, 3->2
        const int jl = zb * 16 + r16;
#pragma unroll
        for (int r = 0; r < 4; ++r)
            Ps[(base_m + r) * VPAD + jl] = 0;
    }
    LDS_BAR();   // Ps + Vt complete and visible

    // ---- O = P V (5 valid k-blocks: kb = (wv>>1)..(wv>>1)+4) ----
    const int kb0 = wv >> 1;
    frag_ab ap[5];
#pragma unroll
    for (int i = 0; i < 5; ++i)
        ap[i] = *(const frag_ab*)&Ps[(wv * 16 + r16) * VPAD + (kb0 + i) * 32 + quad * 8];

    frag_cd oacc[4];
#pragma unroll
    for (int nb = 0; nb < 4; ++nb) oacc[nb] = (frag_cd){0,0,0,0};
    __builtin_amdgcn_s_setprio(1);
#pragma unroll
    for (int nb = 0; nb < 4; ++nb) {
        const int dr  = nb * 16 + r16;
        const int dsw = (dr >> 3) & 7;
#pragma unroll
        for (int i = 0; i < 5; ++i) {
            const int kb = kb0 + i;
            const frag_ab bv = *(const frag_ab*)&Vt[dr * VPAD + (((kb * 4 + quad) ^ dsw) * 8)];
            oacc[nb] = __builtin_amdgcn_mfma_f32_16x16x32_bf16(ap[i], bv, oacc[nb], 0, 0, 0);
        }
    }
    __builtin_amdgcn_s_setprio(0);

    // ---- normalize + store y (bf16) ----
    float inv[4];
#pragma unroll
    for (int r = 0; r < 4; ++r) inv[r] = 1.0f / l[r];
#pragma unroll
    for (int nb = 0; nb < 4; ++nb) {
        const int d  = nb * 16 + r16;
        const uint p01 = pack2(oacc[nb][0] * inv[0], oacc[nb][1] * inv[1]);
        const uint p23 = pack2(oacc[nb][2] * inv[2], oacc[nb][3] * inv[3]);
        const size_t rb = (size_t)(b * T_SZ + qs + base_m) * NE + h * HD + d;
        y[rb + 0 * NE] = (ushort)p01;
        y[rb + 1 * NE] = (ushort)(p01 >> 16);
        y[rb + 2 * NE] = (ushort)p23;
        y[rb + 3 * NE] = (ushort)(p23 >> 16);
    }
}

// =====================================================================
// Kernel 2: LDS-staged NT GEMM, 128m x 64n tile, BK=64 double-buffered
// with COUNTED vmcnt (the correct T3+T4 2-phase):
//   STAGE(next) -> s_waitcnt vmcnt(6)+barrier (cur's 6 oldest loads
//   landed; prefetch stays in flight) -> compute(cur) -> lgkm-only
//   barrier (reads drained; safe to DMA into cur next iter).
// No vmcnt(0) anywhere in the main loop. LDS 48 KiB.
// =====================================================================
#define ASZ (128 * 64)
#define BSZ (64 * 64)

__global__ __launch_bounds__(256, 2) void proj_gemm_kernel(
    const ushort* __restrict__ A,
    const float* __restrict__ bias, float* __restrict__ C)
{
    __shared__ __attribute__((aligned(16))) ushort As[2 * ASZ]; // 32 KiB
    __shared__ __attribute__((aligned(16))) ushort Bs[2 * BSZ]; // 16 KiB

    const ushort* Bw = Wb_static;
    const int t   = threadIdx.x;
    const int bid = blockIdx.x;            // 0..511 flat
    const int swz = ((bid & 7) << 6) | (bid >> 3);  // 512 = 8 XCD * 64
    const int tile_n = swz & 15;           // 0..15
    const int tile_m = swz >> 4;           // 0..31
    const int lane   = t & 63;
    const int wv     = t >> 6;
    const int wm     = wv >> 1;      // 0..1
    const int wn     = wv & 1;       // 0..1
    const int r16    = lane & 15;
    const int quad   = lane >> 4;

    frag_cd acc[4][2];
#pragma unroll
    for (int mi = 0; mi < 4; ++mi)
#pragma unroll
        for (int ni = 0; ni < 2; ++ni)
            acc[mi][ni] = (frag_cd){0.0f, 0.0f, 0.0f, 0.0f};

    const int fm = wm * 64 + r16;            // A row base (add mi*16)
    const int fn = wn * 32 + r16;            // B row base (add ni*16)
    const int sw = r16 & 7;                  // XOR key (row&7 of all frag rows)

    // stage one BK=64 slice into buffer `buf`: 6 global_load_lds / thread
#define STAGE_AB(buf, kk)                                                      \
    {                                                                          \
        _Pragma("unroll")                                                      \
        for (int i = 0; i < 4; ++i) {                                          \
            const int c   = t + 256 * i;                                       \
            const int row = c >> 3;                                            \
            const int src = ((c & 7) ^ (row & 7)) * 8;                         \
            __builtin_amdgcn_global_load_lds(                                  \
                (const __attribute__((address_space(1))) unsigned int*)        \
                    (A + (size_t)(tile_m * 128 + row) * GK + (kk) + src),      \
                (__attribute__((address_space(3))) unsigned int*)              \
                    (As + (buf) * ASZ + c * 8), 16, 0, 0);                     \
        }                                                                      \
        _Pragma("unroll")                                                      \
        for (int i = 0; i < 2; ++i) {                                          \
            const int c   = t + 256 * i;                                       \
            const int row = c >> 3;                                            \
            const int src = ((c & 7) ^ (row & 7)) * 8;                         \
            __builtin_amdgcn_global_load_lds(                                  \
                (const __attribute__((address_space(1))) unsigned int*)        \
                    (Bw + (size_t)(tile_n * 64 + row) * GK + (kk) + src),      \
                (__attribute__((address_space(3))) unsigned int*)              \
                    (Bs + (buf) * BSZ + c * 8), 16, 0, 0);                     \
        }                                                                      \
    }

    // compute one BK=64 slice from buffer `buf`: 12 ds_read_b128, 16 MFMA
#define COMPUTE_AB(buf)                                                        \
    {                                                                          \
        _Pragma("unroll")                                                      \
        for (int ks = 0; ks < 2; ++ks) {                                       \
            const int cidx = (((ks * 4) + quad) ^ sw) * 8;                     \
            frag_ab af[4], bfr[2];                                             \
            _Pragma("unroll")                                                  \
            for (int mi = 0; mi < 4; ++mi)                                     \
                af[mi] = *(const frag_ab*)                                     \
                    &As[(buf) * ASZ + (fm + mi * 16) * 64 + cidx];             \
            _Pragma("unroll")                                                  \
            for (int ni = 0; ni < 2; ++ni)                                     \
                bfr[ni] = *(const frag_ab*)                                    \
                    &Bs[(buf) * BSZ + (fn + ni * 16) * 64 + cidx];             \
            _Pragma("unroll")                                                  \
            for (int mi = 0; mi < 4; ++mi)                                     \
                _Pragma("unroll")                                              \
                for (int ni = 0; ni < 2; ++ni)                                 \
                    acc[mi][ni] = __builtin_amdgcn_mfma_f32_16x16x32_bf16(     \
                        af[mi], bfr[ni], acc[mi][ni], 0, 0, 0);                \
        }                                                                      \
    }

    STAGE_AB(0, 0);
    int cur = 0;
    for (int k0 = 0; k0 < GK - 64; k0 += 64) {
        STAGE_AB(cur ^ 1, k0 + 64);    // prefetch next tile
        VM_BAR(6);                     // cur's 6 loads landed; prefetch lives
        COMPUTE_AB(cur);
        LDS_BAR();                     // reads of cur drained -> reusable
        cur ^= 1;
    }
    {   // last tile: nothing left to prefetch; full drain once
        asm volatile("s_waitcnt vmcnt(0)" ::: "memory");
        __builtin_amdgcn_s_barrier();
        asm volatile("" ::: "memory");
        COMPUTE_AB(cur);
    }

#pragma unroll
    for (int mi = 0; mi < 4; ++mi) {
#pragma unroll
        for (int ni = 0; ni < 2; ++ni) {
            const int rbase = tile_m * 128 + wm * 64 + mi * 16 + quad * 4;
            const int cg    = tile_n * 64 + wn * 32 + ni * 16 + r16;
            const float bv  = bias[cg];
#pragma unroll
            for (int r = 0; r < 4; ++r)
                C[(size_t)(rbase + r) * GN + cg] = acc[mi][ni][r] + bv;
        }
    }
}

extern "C" void kernel_launch(void* const* d_in, const int* in_sizes, int n_in,
                              void* d_out, int out_size, void* d_ws, size_t ws_size,
                              hipStream_t stream) {
    (void)in_sizes; (void)n_in; (void)out_size; (void)ws_size;
    const float* q    = (const float*)d_in[0];
    const float* k    = (const float*)d_in[1];
    const float* v    = (const float*)d_in[2];
    const float* W    = (const float*)d_in[3];
    const float* bias = (const float*)d_in[4];
    float*  out = (float*)d_out;
    ushort* y   = (ushort*)d_ws;   // 8 MiB bf16 scratch

    dim3 g1(1024);                         // flat; XCD-swizzled inside
    attn_mfma_kernel<<<g1, 256, 0, stream>>>(q, k, v, W, y);

    dim3 g2(512);                          // flat; XCD-swizzled inside
    proj_gemm_kernel<<<g2, 256, 0, stream>>>(y, bias, out);
}